// Round 6
// baseline (202.242 us; speedup 1.0000x reference)
//
#include <hip/hip_runtime.h>
#include <math.h>

#define DIM_    128
#define QH_     16
#define KVH_    4
#define WIN_    512
#define BATCH_  4
#define SEQ_    2048
#define QKV_LD  3072
#define ATT_LD  2048

#define NX   (BATCH_*SEQ_*DIM_)   // 1048576
#define NWQ  (DIM_*QKV_LD)        // 393216
#define NWP  (ATT_LD*DIM_)        // 262144

typedef __attribute__((ext_vector_type(8))) short short8;
typedef __attribute__((ext_vector_type(4))) float f32x4;
typedef unsigned short u16;
typedef unsigned int u32;

__device__ __forceinline__ u16 f2bf(float f) {
    u32 u = __float_as_uint(f);
    u += 0x7fff + ((u >> 16) & 1);
    return (u16)(u >> 16);
}
__device__ __forceinline__ float bf2f(u16 u) {
    return __uint_as_float(((u32)u) << 16);
}
// pack 2 f32 -> 2 bf16 (RNE), single VALU instr (no builtin on gfx950)
__device__ __forceinline__ u32 pkbf(float a, float b) {
    u32 r;
    __asm__("v_cvt_pk_bf16_f32 %0, %1, %2" : "=v"(r) : "v"(a), "v"(b));
    return r;
}
#define MFMA16 __builtin_amdgcn_mfma_f32_16x16x32_bf16

#if __has_builtin(__builtin_amdgcn_exp2f)
#define EXP2F __builtin_amdgcn_exp2f
#else
#define EXP2F exp2f
#endif

__device__ __forceinline__ void gload_lds16(const u16* g, u16* l) {
    __builtin_amdgcn_global_load_lds(
        (const __attribute__((address_space(1))) unsigned int*)(const void*)g,
        (__attribute__((address_space(3))) unsigned int*)(void*)l, 16, 0, 0);
}

// ---------- prep: xcvt + wtrans fused (unchanged) --------------------------
__global__ __launch_bounds__(256) void prep(
    const float* __restrict__ x, const float* __restrict__ Wqkv,
    const float* __restrict__ Wproj,
    u16* __restrict__ xh, u16* __restrict__ wth, u16* __restrict__ wpth)
{
    if (blockIdx.x < 1024) {
        const size_t t = (size_t)blockIdx.x * 256 + threadIdx.x;
        float4 v = *(const float4*)(x + 4 * t);
        ushort4 o;
        o.x = f2bf(v.x); o.y = f2bf(v.y); o.z = f2bf(v.z); o.w = f2bf(v.w);
        *(ushort4*)(xh + 4 * t) = o;
        return;
    }
    __shared__ float T[32][33];
    int tile = blockIdx.x - 1024;
    const float* src; u16* dst; int K, N;
    if (tile < 384) { src = Wqkv;  dst = wth;  K = 128;  N = 3072; }
    else { tile -= 384; src = Wproj; dst = wpth; K = 2048; N = 128; }
    const int ntile = N >> 5;
    const int k0 = (tile / ntile) << 5, n0 = (tile % ntile) << 5;
    const int tx = threadIdx.x & 31, ty = threadIdx.x >> 5;
    #pragma unroll
    for (int i = 0; i < 4; ++i)
        T[ty + 8 * i][tx] = src[(size_t)(k0 + ty + 8 * i) * N + n0 + tx];
    __syncthreads();
    #pragma unroll
    for (int i = 0; i < 4; ++i)
        dst[(size_t)(n0 + ty + 8 * i) * K + k0 + tx] = f2bf(T[tx][ty + 8 * i]);
}

// ---------- GEMM1 REWRITE: barrier-free streaming, B-fragments in regs -----
// K=128 fits in registers entirely. Per wave: bf[4][4] (64 VGPR) holds the
// 64-col B-tile as MFMA fragments, loaded ONCE and reused for 8 m-iters of
// 64 rows (wave = 16 rows x 64 cols). A streams global->reg with ping-pong
// double buffering. No LDS, no barriers, no manual waitcnt: the old
// stage(48KB)->barrier->160cyc-compute structure had ~900cyc exposed staging
// latency per block; here loads pipeline under MFMA across m-iters.
// Grid (48 n-tiles, 16 m-chunks of 512 rows) = 768 blocks.
__global__ __launch_bounds__(256) void gemm1_mfma(
    const u16* __restrict__ xh, const u16* __restrict__ wth,
    u16* __restrict__ qkvb, u16* __restrict__ vg)
{
    const int bn = blockIdx.x * 64;
    const int mc = blockIdx.y * 512;
    const int wv = threadIdx.x >> 6, lane = threadIdx.x & 63;
    const int lo = lane & 15, hi = lane >> 4;
    const int lr = lo, quad = hi;

    short8 bf[4][4];                 // 64 VGPR, invariant across m
    #pragma unroll
    for (int nt = 0; nt < 4; ++nt)
        #pragma unroll
        for (int s = 0; s < 4; ++s)
            bf[nt][s] = *(const short8*)(
                wth + (size_t)(bn + nt * 16 + lo) * DIM_ + s * 32 + hi * 8);

    const bool qk = (bn < 2560);
    const u16* aA = xh + (size_t)(mc + wv * 16 + lo) * DIM_ + hi * 8;

#define G1BODY(AF, IT) do {                                                   \
    f32x4 acc[4] = {};                                                        \
    if (qk) {                                                                 \
        _Pragma("unroll")                                                     \
        for (int s = 0; s < 4; ++s)                                           \
            _Pragma("unroll")                                                 \
            for (int nt = 0; nt < 4; ++nt)                                    \
                acc[nt] = MFMA16(bf[nt][s], AF[s], acc[nt], 0, 0, 0);         \
        const int row = mc + (IT) * 64 + wv * 16 + lr;                        \
        u16* dst = qkvb + (size_t)row * QKV_LD + bn + quad * 4;               \
        _Pragma("unroll")                                                     \
        for (int nt = 0; nt < 4; ++nt) {                                      \
            uint2 o;                                                          \
            o.x = pkbf(acc[nt][0], acc[nt][1]);                               \
            o.y = pkbf(acc[nt][2], acc[nt][3]);                               \
            *(uint2*)(dst + nt * 16) = o;                                     \
        }                                                                     \
    } else {                                                                  \
        _Pragma("unroll")                                                     \
        for (int s = 0; s < 4; ++s)                                           \
            _Pragma("unroll")                                                 \
            for (int nt = 0; nt < 4; ++nt)                                    \
                acc[nt] = MFMA16(AF[s], bf[nt][s], acc[nt], 0, 0, 0);         \
        const int m0 = mc + (IT) * 64 + wv * 16 + quad * 4;                   \
        const int bb = m0 >> 11, mseq = m0 & 2047;                            \
        _Pragma("unroll")                                                     \
        for (int nt = 0; nt < 4; ++nt) {                                      \
            const int ncol = bn + nt * 16 + lr - 2560;                        \
            const int kvh = ncol >> 7, d = ncol & 127;                        \
            uint2 o;                                                          \
            o.x = pkbf(acc[nt][0], acc[nt][1]);                               \
            o.y = pkbf(acc[nt][2], acc[nt][3]);                               \
            *(uint2*)(vg + ((size_t)(bb * KVH_ + kvh) * DIM_ + d) * SEQ_      \
                      + mseq) = o;                                            \
        }                                                                     \
    }                                                                         \
} while (0)

    short8 afA[4], afB[4];
    #pragma unroll
    for (int s = 0; s < 4; ++s) afA[s] = *(const short8*)(aA + s * 32);

    #pragma unroll 1
    for (int it = 0; it < 8; it += 2) {
        const u16* aN = aA + (size_t)(it + 1) * 64 * DIM_;
        #pragma unroll
        for (int s = 0; s < 4; ++s) afB[s] = *(const short8*)(aN + s * 32);
        G1BODY(afA, it);
        const int nx = (it + 2 < 8) ? (it + 2) : 7;
        const u16* aN2 = aA + (size_t)nx * 64 * DIM_;
        #pragma unroll
        for (int s = 0; s < 4; ++s) afA[s] = *(const short8*)(aN2 + s * 32);
        G1BODY(afB, it + 1);
    }
#undef G1BODY
}

// ---------- Attention: R5 structure verbatim, split into 2 dispatches ------
// (qoff splits the 64 q-tiles into two 512-block launches: halves attn's
// per-dispatch time to ~37us so non-attn kernels surface in rocprof top-5.)
__global__ __launch_bounds__(512) void attn_mfma(
    const u16* __restrict__ qkvb, const u16* __restrict__ vg,
    u16* __restrict__ ah, int qoff)
{
    const int xcd  = blockIdx.x & 7;
    const int idx  = blockIdx.x >> 3;          // 0..63 per XCD residue
    const int pair = xcd + 8 * (idx & 1);      // 0..15
    const int qt   = (idx >> 1) + qoff;        // 0..63 across both launches
    const int b    = pair >> 2, kvh = pair & 3;
    const int q0 = qt << 5;
    const int tid = threadIdx.x;
    const int wv8 = tid >> 6, lane = tid & 63;
    const int hq = wv8 >> 1, mrow = wv8 & 1;   // head-sub, m-half
    const int lr = lane & 15, quad = lane >> 4;
    const int h = kvh * 4 + hq;
    const bool oddq = (quad & 1) != 0;

    __shared__ u16 Kb[3][8][512];    // 24KB  3-slot ring, sub p = nt*4+s
    __shared__ u16 Vb[3][8][512];    // 24KB  sub p = d-block

    const float scale2 = 0.08838834764831845f * 1.4426950408889634f;
    const float slope2 = exp2f(-0.5f * (float)(h + 1)) * 1.4426950408889634f;
    const int jbase = max(0, q0 - WIN_);
    const int nch = (q0 + 32 - jbase) >> 5;    // 2..17
    const size_t rowb = (size_t)b * SEQ_;
    const u16* kg  = qkvb + rowb * QKV_LD + (QH_ + kvh) * DIM_;
    const u16* vgb = vg + (size_t)(b * KVH_ + kvh) * DIM_ * SEQ_;
    const int lo = lane & 15, hi = lane >> 4;

    short8 qf[4];                    // 16 VGPR: this wave's 16 q-rows
    {
        const u16* qp = qkvb + (rowb + q0 + mrow * 16 + lr) * QKV_LD
                        + h * DIM_ + quad * 8;
        #pragma unroll
        for (int s = 0; s < 4; ++s) qf[s] = *(const short8*)(qp + 32 * s);
    }

    float alpha0;
    {
        const int q = q0 + mrow * 16 + lr;
        const int rm = (q < WIN_) ? q : WIN_;
        alpha0 = slope2 * (float)(q - rm);
    }

    f32x4 O[8] = {};                 // 32 AGPR: O^T, regs = d, lane col = q
    float rs = 0.f;

    #define STAGE(CH, SLOT) do {                                              \
        const int _jk = jbase + ((CH) << 5);                                  \
        gload_lds16(kg + (size_t)(_jk + (wv8 >> 2) * 16 + lo) * QKV_LD        \
                    + (wv8 & 3) * 32 + hi * 8, &Kb[(SLOT)][wv8][0]);          \
        gload_lds16(vgb + (size_t)(wv8 * 16 + lo) * SEQ_ + _jk + hi * 8,      \
                    &Vb[(SLOT)][wv8][0]);                                     \
    } while (0)

    STAGE(0, 0);
    STAGE(1, 1);                      // nch >= 2 always

    for (int ch = 0; ch < nch; ++ch) {
        const int jk = jbase + (ch << 5);
        const int slot = ch % 3;
        __asm__ volatile("s_waitcnt vmcnt(2)" ::: "memory");
        __asm__ volatile("s_barrier" ::: "memory");   // chunk ch staged everywhere
        { const int cn = (ch + 2 < nch) ? (ch + 2) : (nch - 1);
          STAGE(cn, (ch + 2) % 3); }

        u32 pw[2][2];                // [nt][w] packed bf16 pairs
        const int qm0 = q0 + mrow * 16;
        #pragma unroll
        for (int nt = 0; nt < 2; ++nt) {
            f32x4 c = {0.f, 0.f, 0.f, 0.f};
            __builtin_amdgcn_s_setprio(1);
            #pragma unroll
            for (int s = 0; s < 4; ++s) {
                short8 kf = *(const short8*)&Kb[slot][nt * 4 + s][lane * 8];
                c = MFMA16(kf, qf[s], c, 0, 0, 0);
            }
            __builtin_amdgcn_s_setprio(0);
            const int jknt = jk + nt * 16;
            const float b0 = fmaf(-slope2, (float)(jknt + quad * 4), alpha0);
            float e0, e1, e2, e3;
            if (qm0 >= jknt + 15 && qm0 + 15 <= jknt + WIN_) {   // full
                e0 = EXP2F(fmaf(c[0], scale2, b0));
                e1 = EXP2F(fmaf(c[1], scale2, b0 - slope2));
                e2 = EXP2F(fmaf(c[2], scale2, b0 - 2.f * slope2));
                e3 = EXP2F(fmaf(c[3], scale2, b0 - 3.f * slope2));
            } else {                                              // edge
                const int q = qm0 + lr, j0q = jknt + quad * 4;
                float ee[4];
                #pragma unroll
                for (int r = 0; r < 4; ++r) {
                    const int rel = q - (j0q + r);
                    const float t = fmaf(c[r], scale2, b0 - (float)r * slope2);
                    ee[r] = ((unsigned)rel <= (unsigned)WIN_) ? EXP2F(t) : 0.f;
                }
                e0 = ee[0]; e1 = ee[1]; e2 = ee[2]; e3 = ee[3];
            }
            rs += (e0 + e1) + (e2 + e3);
            pw[nt][0] = pkbf(e0, e1);
            pw[nt][1] = pkbf(e2, e3);
        }

        // In-register P^T redistribution (R4-verified lane algebra).
        short8 pa;
        {
            union { u32 w[4]; short8 s; } P;
            #pragma unroll
            for (int w = 0; w < 2; ++w) {
                auto r = __builtin_amdgcn_permlane32_swap(
                    pw[0][w], pw[1][w], false, false);
                const u32 rx = r[0], ry = r[1];
                const u32 sx = (u32)__shfl_xor((int)rx, 16);
                const u32 sy = (u32)__shfl_xor((int)ry, 16);
                P.w[w]     = oddq ? sy : rx;
                P.w[2 + w] = oddq ? ry : sx;
            }
            pa = P.s;
        }

        __builtin_amdgcn_s_setprio(1);
        #pragma unroll
        for (int nt = 0; nt < 8; ++nt) {
            short8 vf = *(const short8*)&Vb[slot][nt][lane * 8];
            O[nt] = MFMA16(vf, pa, O[nt], 0, 0, 0);
        }
        __builtin_amdgcn_s_setprio(0);
    }
    #undef STAGE

    __asm__ volatile("s_waitcnt vmcnt(0)" ::: "memory");

    rs += __shfl_xor(rs, 16);
    rs += __shfl_xor(rs, 32);

    {
        const float inv = 1.0f / rs;
        u16* dst = ah + (rowb + q0 + mrow * 16 + lr) * (size_t)ATT_LD
                   + h * DIM_;
        #pragma unroll
        for (int nt = 0; nt < 8; ++nt) {
            uint2 o;
            o.x = pkbf(O[nt][0] * inv, O[nt][1] * inv);
            o.y = pkbf(O[nt][2] * inv, O[nt][3] * inv);
            *(uint2*)(dst + nt * 16 + quad * 4) = o;
        }
    }
}

// ---------- GEMM2: 16-row blocks, wave = col-quarter (unchanged) -----------
__global__ __launch_bounds__(256) void gemm2_mfma(
    const u16* __restrict__ ah, const u16* __restrict__ wpth,
    float* __restrict__ out)
{
    const int bm = blockIdx.x * 16;
    const int wv = threadIdx.x >> 6, lane = threadIdx.x & 63;
    const int lr = lane & 15, quad = lane >> 4;
    const int cq = wv;

    const u16* arow  = ah + (size_t)(bm + lr) * ATT_LD + quad * 8;
    const u16* w0row = wpth + (size_t)(cq * 32 + lr) * ATT_LD + quad * 8;
    const u16* w1row = w0row + (size_t)16 * ATT_LD;

    f32x4 acc0 = {0.f, 0.f, 0.f, 0.f}, acc1 = {0.f, 0.f, 0.f, 0.f};
    #pragma unroll 8
    for (int k0 = 0; k0 < ATT_LD; k0 += 32) {
        short8 a  = *(const short8*)(arow + k0);
        short8 w0 = *(const short8*)(w0row + k0);
        short8 w1 = *(const short8*)(w1row + k0);
        acc0 = MFMA16(w0, a, acc0, 0, 0, 0);
        acc1 = MFMA16(w1, a, acc1, 0, 0, 0);
    }
    float* orow = out + (size_t)(bm + lr) * DIM_ + cq * 32;
    *(float4*)(orow + quad * 4)      = *(float4*)&acc0;
    *(float4*)(orow + 16 + quad * 4) = *(float4*)&acc1;
}

// ---------- launch ----------------------------------------------------------
extern "C" void kernel_launch(void* const* d_in, const int* in_sizes, int n_in,
                              void* d_out, int out_size, void* d_ws, size_t ws_size,
                              hipStream_t stream)
{
    const float* x     = (const float*)d_in[0];
    const float* Wqkv  = (const float*)d_in[1];
    const float* Wproj = (const float*)d_in[2];
    float* out = (float*)d_out;

    u16* xh   = (u16*)d_ws;
    u16* wth  = xh   + (size_t)NX;
    u16* wpth = wth  + (size_t)NWQ;
    u16* qkvb = wpth + (size_t)NWP;                         // 8192*3072
    u16* vg   = qkvb + (size_t)8192 * QKV_LD;               // 4*4*128*2048
    u16* ahp  = vg   + (size_t)BATCH_ * KVH_ * DIM_ * SEQ_; // 8192*2048

    prep<<<1024 + 640, 256, 0, stream>>>(x, Wqkv, Wproj, xh, wth, wpth);

    gemm1_mfma<<<dim3(48, 16), 256, 0, stream>>>(xh, wth, qkvb, vg);

    attn_mfma<<<512, 512, 0, stream>>>(qkvb, vg, ahp, 0);
    attn_mfma<<<512, 512, 0, stream>>>(qkvb, vg, ahp, 32);

    gemm2_mfma<<<8192 / 16, 256, 0, stream>>>(ahp, wpth, out);
}

// Round 7
// 201.322 us; speedup vs baseline: 1.0046x; 1.0046x over previous
//
#include <hip/hip_runtime.h>
#include <math.h>

#define DIM_    128
#define QH_     16
#define KVH_    4
#define WIN_    512
#define BATCH_  4
#define SEQ_    2048
#define QKV_LD  3072
#define ATT_LD  2048

#define NX   (BATCH_*SEQ_*DIM_)   // 1048576
#define NWQ  (DIM_*QKV_LD)        // 393216
#define NWP  (ATT_LD*DIM_)        // 262144

typedef __attribute__((ext_vector_type(8))) short short8;
typedef __attribute__((ext_vector_type(4))) float f32x4;
typedef unsigned short u16;
typedef unsigned int u32;

__device__ __forceinline__ u16 f2bf(float f) {
    u32 u = __float_as_uint(f);
    u += 0x7fff + ((u >> 16) & 1);
    return (u16)(u >> 16);
}
__device__ __forceinline__ float bf2f(u16 u) {
    return __uint_as_float(((u32)u) << 16);
}
// pack 2 f32 -> 2 bf16 (RNE), single VALU instr (no builtin on gfx950)
__device__ __forceinline__ u32 pkbf(float a, float b) {
    u32 r;
    __asm__("v_cvt_pk_bf16_f32 %0, %1, %2" : "=v"(r) : "v"(a), "v"(b));
    return r;
}
#define MFMA16 __builtin_amdgcn_mfma_f32_16x16x32_bf16

#if __has_builtin(__builtin_amdgcn_exp2f)
#define EXP2F __builtin_amdgcn_exp2f
#else
#define EXP2F exp2f
#endif

__device__ __forceinline__ void gload_lds16(const u16* g, u16* l) {
    __builtin_amdgcn_global_load_lds(
        (const __attribute__((address_space(1))) unsigned int*)(const void*)g,
        (__attribute__((address_space(3))) unsigned int*)(void*)l, 16, 0, 0);
}

// ---------- prep: xcvt + wtrans fused (unchanged) --------------------------
__global__ __launch_bounds__(256) void prep(
    const float* __restrict__ x, const float* __restrict__ Wqkv,
    const float* __restrict__ Wproj,
    u16* __restrict__ xh, u16* __restrict__ wth, u16* __restrict__ wpth)
{
    if (blockIdx.x < 1024) {
        const size_t t = (size_t)blockIdx.x * 256 + threadIdx.x;
        float4 v = *(const float4*)(x + 4 * t);
        ushort4 o;
        o.x = f2bf(v.x); o.y = f2bf(v.y); o.z = f2bf(v.z); o.w = f2bf(v.w);
        *(ushort4*)(xh + 4 * t) = o;
        return;
    }
    __shared__ float T[32][33];
    int tile = blockIdx.x - 1024;
    const float* src; u16* dst; int K, N;
    if (tile < 384) { src = Wqkv;  dst = wth;  K = 128;  N = 3072; }
    else { tile -= 384; src = Wproj; dst = wpth; K = 2048; N = 128; }
    const int ntile = N >> 5;
    const int k0 = (tile / ntile) << 5, n0 = (tile % ntile) << 5;
    const int tx = threadIdx.x & 31, ty = threadIdx.x >> 5;
    #pragma unroll
    for (int i = 0; i < 4; ++i)
        T[ty + 8 * i][tx] = src[(size_t)(k0 + ty + 8 * i) * N + n0 + tx];
    __syncthreads();
    #pragma unroll
    for (int i = 0; i < 4; ++i)
        dst[(size_t)(n0 + ty + 8 * i) * K + k0 + tx] = f2bf(T[tx][ty + 8 * i]);
}

// ---------- GEMM1: barrier-free streaming, B-fragments in regs (R6) --------
__global__ __launch_bounds__(256) void gemm1_mfma(
    const u16* __restrict__ xh, const u16* __restrict__ wth,
    u16* __restrict__ qkvb, u16* __restrict__ vg)
{
    const int bn = blockIdx.x * 64;
    const int mc = blockIdx.y * 512;
    const int wv = threadIdx.x >> 6, lane = threadIdx.x & 63;
    const int lo = lane & 15, hi = lane >> 4;
    const int lr = lo, quad = hi;

    short8 bf[4][4];                 // 64 VGPR, invariant across m
    #pragma unroll
    for (int nt = 0; nt < 4; ++nt)
        #pragma unroll
        for (int s = 0; s < 4; ++s)
            bf[nt][s] = *(const short8*)(
                wth + (size_t)(bn + nt * 16 + lo) * DIM_ + s * 32 + hi * 8);

    const bool qk = (bn < 2560);
    const u16* aA = xh + (size_t)(mc + wv * 16 + lo) * DIM_ + hi * 8;

#define G1BODY(AF, IT) do {                                                   \
    f32x4 acc[4] = {};                                                        \
    if (qk) {                                                                 \
        _Pragma("unroll")                                                     \
        for (int s = 0; s < 4; ++s)                                           \
            _Pragma("unroll")                                                 \
            for (int nt = 0; nt < 4; ++nt)                                    \
                acc[nt] = MFMA16(bf[nt][s], AF[s], acc[nt], 0, 0, 0);         \
        const int row = mc + (IT) * 64 + wv * 16 + lr;                        \
        u16* dst = qkvb + (size_t)row * QKV_LD + bn + quad * 4;               \
        _Pragma("unroll")                                                     \
        for (int nt = 0; nt < 4; ++nt) {                                      \
            uint2 o;                                                          \
            o.x = pkbf(acc[nt][0], acc[nt][1]);                               \
            o.y = pkbf(acc[nt][2], acc[nt][3]);                               \
            *(uint2*)(dst + nt * 16) = o;                                     \
        }                                                                     \
    } else {                                                                  \
        _Pragma("unroll")                                                     \
        for (int s = 0; s < 4; ++s)                                           \
            _Pragma("unroll")                                                 \
            for (int nt = 0; nt < 4; ++nt)                                    \
                acc[nt] = MFMA16(AF[s], bf[nt][s], acc[nt], 0, 0, 0);         \
        const int m0 = mc + (IT) * 64 + wv * 16 + quad * 4;                   \
        const int bb = m0 >> 11, mseq = m0 & 2047;                            \
        _Pragma("unroll")                                                     \
        for (int nt = 0; nt < 4; ++nt) {                                      \
            const int ncol = bn + nt * 16 + lr - 2560;                        \
            const int kvh = ncol >> 7, d = ncol & 127;                        \
            uint2 o;                                                          \
            o.x = pkbf(acc[nt][0], acc[nt][1]);                               \
            o.y = pkbf(acc[nt][2], acc[nt][3]);                               \
            *(uint2*)(vg + ((size_t)(bb * KVH_ + kvh) * DIM_ + d) * SEQ_      \
                      + mseq) = o;                                            \
        }                                                                     \
    }                                                                         \
} while (0)

    short8 afA[4], afB[4];
    #pragma unroll
    for (int s = 0; s < 4; ++s) afA[s] = *(const short8*)(aA + s * 32);

    #pragma unroll 1
    for (int it = 0; it < 8; it += 2) {
        const u16* aN = aA + (size_t)(it + 1) * 64 * DIM_;
        #pragma unroll
        for (int s = 0; s < 4; ++s) afB[s] = *(const short8*)(aN + s * 32);
        G1BODY(afA, it);
        const int nx = (it + 2 < 8) ? (it + 2) : 7;
        const u16* aN2 = aA + (size_t)nx * 64 * DIM_;
        #pragma unroll
        for (int s = 0; s < 4; ++s) afA[s] = *(const short8*)(aN2 + s * 32);
        G1BODY(afB, it + 1);
    }
#undef G1BODY
}

// ---------- Attention: R5 structure verbatim, split into 2 dispatches ------
__global__ __launch_bounds__(512) void attn_mfma(
    const u16* __restrict__ qkvb, const u16* __restrict__ vg,
    u16* __restrict__ ah, int qoff)
{
    const int xcd  = blockIdx.x & 7;
    const int idx  = blockIdx.x >> 3;          // 0..63 per XCD residue
    const int pair = xcd + 8 * (idx & 1);      // 0..15
    const int qt   = (idx >> 1) + qoff;        // 0..63 across both launches
    const int b    = pair >> 2, kvh = pair & 3;
    const int q0 = qt << 5;
    const int tid = threadIdx.x;
    const int wv8 = tid >> 6, lane = tid & 63;
    const int hq = wv8 >> 1, mrow = wv8 & 1;   // head-sub, m-half
    const int lr = lane & 15, quad = lane >> 4;
    const int h = kvh * 4 + hq;
    const bool oddq = (quad & 1) != 0;

    __shared__ u16 Kb[3][8][512];    // 24KB  3-slot ring, sub p = nt*4+s
    __shared__ u16 Vb[3][8][512];    // 24KB  sub p = d-block

    const float scale2 = 0.08838834764831845f * 1.4426950408889634f;
    const float slope2 = exp2f(-0.5f * (float)(h + 1)) * 1.4426950408889634f;
    const int jbase = max(0, q0 - WIN_);
    const int nch = (q0 + 32 - jbase) >> 5;    // 2..17
    const size_t rowb = (size_t)b * SEQ_;
    const u16* kg  = qkvb + rowb * QKV_LD + (QH_ + kvh) * DIM_;
    const u16* vgb = vg + (size_t)(b * KVH_ + kvh) * DIM_ * SEQ_;
    const int lo = lane & 15, hi = lane >> 4;

    short8 qf[4];                    // 16 VGPR: this wave's 16 q-rows
    {
        const u16* qp = qkvb + (rowb + q0 + mrow * 16 + lr) * QKV_LD
                        + h * DIM_ + quad * 8;
        #pragma unroll
        for (int s = 0; s < 4; ++s) qf[s] = *(const short8*)(qp + 32 * s);
    }

    float alpha0;
    {
        const int q = q0 + mrow * 16 + lr;
        const int rm = (q < WIN_) ? q : WIN_;
        alpha0 = slope2 * (float)(q - rm);
    }

    f32x4 O[8] = {};                 // 32 AGPR: O^T, regs = d, lane col = q
    float rs = 0.f;

    #define STAGE(CH, SLOT) do {                                              \
        const int _jk = jbase + ((CH) << 5);                                  \
        gload_lds16(kg + (size_t)(_jk + (wv8 >> 2) * 16 + lo) * QKV_LD        \
                    + (wv8 & 3) * 32 + hi * 8, &Kb[(SLOT)][wv8][0]);          \
        gload_lds16(vgb + (size_t)(wv8 * 16 + lo) * SEQ_ + _jk + hi * 8,      \
                    &Vb[(SLOT)][wv8][0]);                                     \
    } while (0)

    STAGE(0, 0);
    STAGE(1, 1);                      // nch >= 2 always

    for (int ch = 0; ch < nch; ++ch) {
        const int jk = jbase + (ch << 5);
        const int slot = ch % 3;
        __asm__ volatile("s_waitcnt vmcnt(2)" ::: "memory");
        __asm__ volatile("s_barrier" ::: "memory");   // chunk ch staged everywhere
        { const int cn = (ch + 2 < nch) ? (ch + 2) : (nch - 1);
          STAGE(cn, (ch + 2) % 3); }

        u32 pw[2][2];                // [nt][w] packed bf16 pairs
        const int qm0 = q0 + mrow * 16;
        #pragma unroll
        for (int nt = 0; nt < 2; ++nt) {
            f32x4 c = {0.f, 0.f, 0.f, 0.f};
            __builtin_amdgcn_s_setprio(1);
            #pragma unroll
            for (int s = 0; s < 4; ++s) {
                short8 kf = *(const short8*)&Kb[slot][nt * 4 + s][lane * 8];
                c = MFMA16(kf, qf[s], c, 0, 0, 0);
            }
            __builtin_amdgcn_s_setprio(0);
            const int jknt = jk + nt * 16;
            const float b0 = fmaf(-slope2, (float)(jknt + quad * 4), alpha0);
            float e0, e1, e2, e3;
            if (qm0 >= jknt + 15 && qm0 + 15 <= jknt + WIN_) {   // full
                e0 = EXP2F(fmaf(c[0], scale2, b0));
                e1 = EXP2F(fmaf(c[1], scale2, b0 - slope2));
                e2 = EXP2F(fmaf(c[2], scale2, b0 - 2.f * slope2));
                e3 = EXP2F(fmaf(c[3], scale2, b0 - 3.f * slope2));
            } else {                                              // edge
                const int q = qm0 + lr, j0q = jknt + quad * 4;
                float ee[4];
                #pragma unroll
                for (int r = 0; r < 4; ++r) {
                    const int rel = q - (j0q + r);
                    const float t = fmaf(c[r], scale2, b0 - (float)r * slope2);
                    ee[r] = ((unsigned)rel <= (unsigned)WIN_) ? EXP2F(t) : 0.f;
                }
                e0 = ee[0]; e1 = ee[1]; e2 = ee[2]; e3 = ee[3];
            }
            rs += (e0 + e1) + (e2 + e3);
            pw[nt][0] = pkbf(e0, e1);
            pw[nt][1] = pkbf(e2, e3);
        }

        // In-register P^T redistribution (R4-verified lane algebra).
        short8 pa;
        {
            union { u32 w[4]; short8 s; } P;
            #pragma unroll
            for (int w = 0; w < 2; ++w) {
                auto r = __builtin_amdgcn_permlane32_swap(
                    pw[0][w], pw[1][w], false, false);
                const u32 rx = r[0], ry = r[1];
                const u32 sx = (u32)__shfl_xor((int)rx, 16);
                const u32 sy = (u32)__shfl_xor((int)ry, 16);
                P.w[w]     = oddq ? sy : rx;
                P.w[2 + w] = oddq ? ry : sx;
            }
            pa = P.s;
        }

        __builtin_amdgcn_s_setprio(1);
        #pragma unroll
        for (int nt = 0; nt < 8; ++nt) {
            short8 vf = *(const short8*)&Vb[slot][nt][lane * 8];
            O[nt] = MFMA16(vf, pa, O[nt], 0, 0, 0);
        }
        __builtin_amdgcn_s_setprio(0);
    }
    #undef STAGE

    __asm__ volatile("s_waitcnt vmcnt(0)" ::: "memory");

    rs += __shfl_xor(rs, 16);
    rs += __shfl_xor(rs, 32);

    {
        const float inv = 1.0f / rs;
        u16* dst = ah + (rowb + q0 + mrow * 16 + lr) * (size_t)ATT_LD
                   + h * DIM_;
        #pragma unroll
        for (int nt = 0; nt < 8; ++nt) {
            uint2 o;
            o.x = pkbf(O[nt][0] * inv, O[nt][1] * inv);
            o.y = pkbf(O[nt][2] * inv, O[nt][3] * inv);
            *(uint2*)(dst + nt * 16 + quad * 4) = o;
        }
    }
}

// ---------- GEMM2 REWRITE: intra-block split-K + ping-pong prefetch --------
// R6 counters: 45.7us, MfmaUtil 3.1%, occ 19%, VGPR 28 -> pure latency
// serialization (64 dependent K-iters, no regs to pipeline). Fix:
//  - 8 waves/block (512 thr): waves 0-3 take K[0,1024), waves 4-7 take
//    K[1024,2048). Halves the chain (32 iters) and doubles TLP to 16
//    waves/CU. Halves combined via 8KB LDS + one __syncthreads.
//  - explicit ping-pong register prefetch (R5-gemm1 pattern): next k-step's
//    a/w fragments load while current step's MFMAs run.
// Traffic floor ~38MB (A 33.5 HBM + out 4; W L2-resident) ~= 6us.
__global__ __launch_bounds__(512) void gemm2_mfma(
    const u16* __restrict__ ah, const u16* __restrict__ wpth,
    float* __restrict__ out)
{
    const int bm = blockIdx.x * 16;
    const int wv = threadIdx.x >> 6, lane = threadIdx.x & 63;
    const int lr = lane & 15, quad = lane >> 4;
    const int cq = wv & 3, kg = wv >> 2;

    __shared__ float red[4][64][8];  // 8KB: kg=1 partials

    const u16* arow  = ah + (size_t)(bm + lr) * ATT_LD + kg * 1024 + quad * 8;
    const u16* w0row = wpth + (size_t)(cq * 32 + lr) * ATT_LD + kg * 1024
                       + quad * 8;
    const u16* w1row = w0row + (size_t)16 * ATT_LD;

    f32x4 acc0 = {0.f, 0.f, 0.f, 0.f}, acc1 = {0.f, 0.f, 0.f, 0.f};

    short8 aA  = *(const short8*)(arow);
    short8 w0A = *(const short8*)(w0row);
    short8 w1A = *(const short8*)(w1row);

    #pragma unroll 4
    for (int k0 = 0; k0 < 1024; k0 += 64) {
        short8 aB  = *(const short8*)(arow  + k0 + 32);
        short8 w0B = *(const short8*)(w0row + k0 + 32);
        short8 w1B = *(const short8*)(w1row + k0 + 32);
        acc0 = MFMA16(w0A, aA, acc0, 0, 0, 0);
        acc1 = MFMA16(w1A, aA, acc1, 0, 0, 0);
        const int nx = (k0 + 64 < 1024) ? (k0 + 64) : 0;   // clamped prefetch
        aA  = *(const short8*)(arow  + nx);
        w0A = *(const short8*)(w0row + nx);
        w1A = *(const short8*)(w1row + nx);
        acc0 = MFMA16(w0B, aB, acc0, 0, 0, 0);
        acc1 = MFMA16(w1B, aB, acc1, 0, 0, 0);
    }

    if (kg == 1) {
        *(float4*)&red[cq][lane][0] = *(float4*)&acc0;
        *(float4*)&red[cq][lane][4] = *(float4*)&acc1;
    }
    __syncthreads();
    if (kg == 0) {
        const float4 r0 = *(const float4*)&red[cq][lane][0];
        const float4 r1 = *(const float4*)&red[cq][lane][4];
        acc0[0] += r0.x; acc0[1] += r0.y; acc0[2] += r0.z; acc0[3] += r0.w;
        acc1[0] += r1.x; acc1[1] += r1.y; acc1[2] += r1.z; acc1[3] += r1.w;
        float* orow = out + (size_t)(bm + lr) * DIM_ + cq * 32;
        *(float4*)(orow + quad * 4)      = *(float4*)&acc0;
        *(float4*)(orow + 16 + quad * 4) = *(float4*)&acc1;
    }
}

// ---------- launch ----------------------------------------------------------
extern "C" void kernel_launch(void* const* d_in, const int* in_sizes, int n_in,
                              void* d_out, int out_size, void* d_ws, size_t ws_size,
                              hipStream_t stream)
{
    const float* x     = (const float*)d_in[0];
    const float* Wqkv  = (const float*)d_in[1];
    const float* Wproj = (const float*)d_in[2];
    float* out = (float*)d_out;

    u16* xh   = (u16*)d_ws;
    u16* wth  = xh   + (size_t)NX;
    u16* wpth = wth  + (size_t)NWQ;
    u16* qkvb = wpth + (size_t)NWP;                         // 8192*3072
    u16* vg   = qkvb + (size_t)8192 * QKV_LD;               // 4*4*128*2048
    u16* ahp  = vg   + (size_t)BATCH_ * KVH_ * DIM_ * SEQ_; // 8192*2048

    prep<<<1024 + 640, 256, 0, stream>>>(x, Wqkv, Wproj, xh, wth, wpth);

    gemm1_mfma<<<dim3(48, 16), 256, 0, stream>>>(xh, wth, qkvb, vg);

    attn_mfma<<<512, 512, 0, stream>>>(qkvb, vg, ahp, 0);
    attn_mfma<<<512, 512, 0, stream>>>(qkvb, vg, ahp, 32);

    gemm2_mfma<<<8192 / 16, 512, 0, stream>>>(ahp, wpth, out);
}

// Round 8
// 198.402 us; speedup vs baseline: 1.0194x; 1.0147x over previous
//
#include <hip/hip_runtime.h>
#include <math.h>

#define DIM_    128
#define QH_     16
#define KVH_    4
#define WIN_    512
#define BATCH_  4
#define SEQ_    2048
#define QKV_LD  3072
#define ATT_LD  2048

#define NX   (BATCH_*SEQ_*DIM_)   // 1048576
#define NWQ  (DIM_*QKV_LD)        // 393216
#define NWP  (ATT_LD*DIM_)        // 262144

typedef __attribute__((ext_vector_type(8))) short short8;
typedef __attribute__((ext_vector_type(4))) float f32x4;
typedef unsigned short u16;
typedef unsigned int u32;

__device__ __forceinline__ u16 f2bf(float f) {
    u32 u = __float_as_uint(f);
    u += 0x7fff + ((u >> 16) & 1);
    return (u16)(u >> 16);
}
__device__ __forceinline__ float bf2f(u16 u) {
    return __uint_as_float(((u32)u) << 16);
}
// pack 2 f32 -> 2 bf16 (RNE), single VALU instr (no builtin on gfx950)
__device__ __forceinline__ u32 pkbf(float a, float b) {
    u32 r;
    __asm__("v_cvt_pk_bf16_f32 %0, %1, %2" : "=v"(r) : "v"(a), "v"(b));
    return r;
}
#define MFMA16 __builtin_amdgcn_mfma_f32_16x16x32_bf16

#if __has_builtin(__builtin_amdgcn_exp2f)
#define EXP2F __builtin_amdgcn_exp2f
#else
#define EXP2F exp2f
#endif

__device__ __forceinline__ void gload_lds16(const u16* g, u16* l) {
    __builtin_amdgcn_global_load_lds(
        (const __attribute__((address_space(1))) unsigned int*)(const void*)g,
        (__attribute__((address_space(3))) unsigned int*)(void*)l, 16, 0, 0);
}

// ---------- prep: xcvt + wtrans fused (unchanged) --------------------------
__global__ __launch_bounds__(256) void prep(
    const float* __restrict__ x, const float* __restrict__ Wqkv,
    const float* __restrict__ Wproj,
    u16* __restrict__ xh, u16* __restrict__ wth, u16* __restrict__ wpth)
{
    if (blockIdx.x < 1024) {
        const size_t t = (size_t)blockIdx.x * 256 + threadIdx.x;
        float4 v = *(const float4*)(x + 4 * t);
        ushort4 o;
        o.x = f2bf(v.x); o.y = f2bf(v.y); o.z = f2bf(v.z); o.w = f2bf(v.w);
        *(ushort4*)(xh + 4 * t) = o;
        return;
    }
    __shared__ float T[32][33];
    int tile = blockIdx.x - 1024;
    const float* src; u16* dst; int K, N;
    if (tile < 384) { src = Wqkv;  dst = wth;  K = 128;  N = 3072; }
    else { tile -= 384; src = Wproj; dst = wpth; K = 2048; N = 128; }
    const int ntile = N >> 5;
    const int k0 = (tile / ntile) << 5, n0 = (tile % ntile) << 5;
    const int tx = threadIdx.x & 31, ty = threadIdx.x >> 5;
    #pragma unroll
    for (int i = 0; i < 4; ++i)
        T[ty + 8 * i][tx] = src[(size_t)(k0 + ty + 8 * i) * N + n0 + tx];
    __syncthreads();
    #pragma unroll
    for (int i = 0; i < 4; ++i)
        dst[(size_t)(n0 + ty + 8 * i) * K + k0 + tx] = f2bf(T[tx][ty + 8 * i]);
}

// ---------- GEMM1: barrier-free streaming, B-fragments in regs (R6) --------
__global__ __launch_bounds__(256) void gemm1_mfma(
    const u16* __restrict__ xh, const u16* __restrict__ wth,
    u16* __restrict__ qkvb, u16* __restrict__ vg)
{
    const int bn = blockIdx.x * 64;
    const int mc = blockIdx.y * 512;
    const int wv = threadIdx.x >> 6, lane = threadIdx.x & 63;
    const int lo = lane & 15, hi = lane >> 4;
    const int lr = lo, quad = hi;

    short8 bf[4][4];                 // 64 VGPR, invariant across m
    #pragma unroll
    for (int nt = 0; nt < 4; ++nt)
        #pragma unroll
        for (int s = 0; s < 4; ++s)
            bf[nt][s] = *(const short8*)(
                wth + (size_t)(bn + nt * 16 + lo) * DIM_ + s * 32 + hi * 8);

    const bool qk = (bn < 2560);
    const u16* aA = xh + (size_t)(mc + wv * 16 + lo) * DIM_ + hi * 8;

#define G1BODY(AF, IT) do {                                                   \
    f32x4 acc[4] = {};                                                        \
    if (qk) {                                                                 \
        _Pragma("unroll")                                                     \
        for (int s = 0; s < 4; ++s)                                           \
            _Pragma("unroll")                                                 \
            for (int nt = 0; nt < 4; ++nt)                                    \
                acc[nt] = MFMA16(bf[nt][s], AF[s], acc[nt], 0, 0, 0);         \
        const int row = mc + (IT) * 64 + wv * 16 + lr;                        \
        u16* dst = qkvb + (size_t)row * QKV_LD + bn + quad * 4;               \
        _Pragma("unroll")                                                     \
        for (int nt = 0; nt < 4; ++nt) {                                      \
            uint2 o;                                                          \
            o.x = pkbf(acc[nt][0], acc[nt][1]);                               \
            o.y = pkbf(acc[nt][2], acc[nt][3]);                               \
            *(uint2*)(dst + nt * 16) = o;                                     \
        }                                                                     \
    } else {                                                                  \
        _Pragma("unroll")                                                     \
        for (int s = 0; s < 4; ++s)                                           \
            _Pragma("unroll")                                                 \
            for (int nt = 0; nt < 4; ++nt)                                    \
                acc[nt] = MFMA16(AF[s], bf[nt][s], acc[nt], 0, 0, 0);         \
        const int m0 = mc + (IT) * 64 + wv * 16 + quad * 4;                   \
        const int bb = m0 >> 11, mseq = m0 & 2047;                            \
        _Pragma("unroll")                                                     \
        for (int nt = 0; nt < 4; ++nt) {                                      \
            const int ncol = bn + nt * 16 + lr - 2560;                        \
            const int kvh = ncol >> 7, d = ncol & 127;                        \
            uint2 o;                                                          \
            o.x = pkbf(acc[nt][0], acc[nt][1]);                               \
            o.y = pkbf(acc[nt][2], acc[nt][3]);                               \
            *(uint2*)(vg + ((size_t)(bb * KVH_ + kvh) * DIM_ + d) * SEQ_      \
                      + mseq) = o;                                            \
        }                                                                     \
    }                                                                         \
} while (0)

    short8 afA[4], afB[4];
    #pragma unroll
    for (int s = 0; s < 4; ++s) afA[s] = *(const short8*)(aA + s * 32);

    #pragma unroll 1
    for (int it = 0; it < 8; it += 2) {
        const u16* aN = aA + (size_t)(it + 1) * 64 * DIM_;
        #pragma unroll
        for (int s = 0; s < 4; ++s) afB[s] = *(const short8*)(aN + s * 32);
        G1BODY(afA, it);
        const int nx = (it + 2 < 8) ? (it + 2) : 7;
        const u16* aN2 = aA + (size_t)nx * 64 * DIM_;
        #pragma unroll
        for (int s = 0; s < 4; ++s) afA[s] = *(const short8*)(aN2 + s * 32);
        G1BODY(afB, it + 1);
    }
#undef G1BODY
}

// ---------- Attention: R5 structure verbatim, split into 2 dispatches ------
__global__ __launch_bounds__(512) void attn_mfma(
    const u16* __restrict__ qkvb, const u16* __restrict__ vg,
    u16* __restrict__ ah, int qoff)
{
    const int xcd  = blockIdx.x & 7;
    const int idx  = blockIdx.x >> 3;          // 0..63 per XCD residue
    const int pair = xcd + 8 * (idx & 1);      // 0..15
    const int qt   = (idx >> 1) + qoff;        // 0..63 across both launches
    const int b    = pair >> 2, kvh = pair & 3;
    const int q0 = qt << 5;
    const int tid = threadIdx.x;
    const int wv8 = tid >> 6, lane = tid & 63;
    const int hq = wv8 >> 1, mrow = wv8 & 1;   // head-sub, m-half
    const int lr = lane & 15, quad = lane >> 4;
    const int h = kvh * 4 + hq;
    const bool oddq = (quad & 1) != 0;

    __shared__ u16 Kb[3][8][512];    // 24KB  3-slot ring, sub p = nt*4+s
    __shared__ u16 Vb[3][8][512];    // 24KB  sub p = d-block

    const float scale2 = 0.08838834764831845f * 1.4426950408889634f;
    const float slope2 = exp2f(-0.5f * (float)(h + 1)) * 1.4426950408889634f;
    const int jbase = max(0, q0 - WIN_);
    const int nch = (q0 + 32 - jbase) >> 5;    // 2..17
    const size_t rowb = (size_t)b * SEQ_;
    const u16* kg  = qkvb + rowb * QKV_LD + (QH_ + kvh) * DIM_;
    const u16* vgb = vg + (size_t)(b * KVH_ + kvh) * DIM_ * SEQ_;
    const int lo = lane & 15, hi = lane >> 4;

    short8 qf[4];                    // 16 VGPR: this wave's 16 q-rows
    {
        const u16* qp = qkvb + (rowb + q0 + mrow * 16 + lr) * QKV_LD
                        + h * DIM_ + quad * 8;
        #pragma unroll
        for (int s = 0; s < 4; ++s) qf[s] = *(const short8*)(qp + 32 * s);
    }

    float alpha0;
    {
        const int q = q0 + mrow * 16 + lr;
        const int rm = (q < WIN_) ? q : WIN_;
        alpha0 = slope2 * (float)(q - rm);
    }

    f32x4 O[8] = {};                 // 32 AGPR: O^T, regs = d, lane col = q
    float rs = 0.f;

    #define STAGE(CH, SLOT) do {                                              \
        const int _jk = jbase + ((CH) << 5);                                  \
        gload_lds16(kg + (size_t)(_jk + (wv8 >> 2) * 16 + lo) * QKV_LD        \
                    + (wv8 & 3) * 32 + hi * 8, &Kb[(SLOT)][wv8][0]);          \
        gload_lds16(vgb + (size_t)(wv8 * 16 + lo) * SEQ_ + _jk + hi * 8,      \
                    &Vb[(SLOT)][wv8][0]);                                     \
    } while (0)

    STAGE(0, 0);
    STAGE(1, 1);                      // nch >= 2 always

    for (int ch = 0; ch < nch; ++ch) {
        const int jk = jbase + (ch << 5);
        const int slot = ch % 3;
        __asm__ volatile("s_waitcnt vmcnt(2)" ::: "memory");
        __asm__ volatile("s_barrier" ::: "memory");   // chunk ch staged everywhere
        { const int cn = (ch + 2 < nch) ? (ch + 2) : (nch - 1);
          STAGE(cn, (ch + 2) % 3); }

        u32 pw[2][2];                // [nt][w] packed bf16 pairs
        const int qm0 = q0 + mrow * 16;
        #pragma unroll
        for (int nt = 0; nt < 2; ++nt) {
            f32x4 c = {0.f, 0.f, 0.f, 0.f};
            __builtin_amdgcn_s_setprio(1);
            #pragma unroll
            for (int s = 0; s < 4; ++s) {
                short8 kf = *(const short8*)&Kb[slot][nt * 4 + s][lane * 8];
                c = MFMA16(kf, qf[s], c, 0, 0, 0);
            }
            __builtin_amdgcn_s_setprio(0);
            const int jknt = jk + nt * 16;
            const float b0 = fmaf(-slope2, (float)(jknt + quad * 4), alpha0);
            float e0, e1, e2, e3;
            if (qm0 >= jknt + 15 && qm0 + 15 <= jknt + WIN_) {   // full
                e0 = EXP2F(fmaf(c[0], scale2, b0));
                e1 = EXP2F(fmaf(c[1], scale2, b0 - slope2));
                e2 = EXP2F(fmaf(c[2], scale2, b0 - 2.f * slope2));
                e3 = EXP2F(fmaf(c[3], scale2, b0 - 3.f * slope2));
            } else {                                              // edge
                const int q = qm0 + lr, j0q = jknt + quad * 4;
                float ee[4];
                #pragma unroll
                for (int r = 0; r < 4; ++r) {
                    const int rel = q - (j0q + r);
                    const float t = fmaf(c[r], scale2, b0 - (float)r * slope2);
                    ee[r] = ((unsigned)rel <= (unsigned)WIN_) ? EXP2F(t) : 0.f;
                }
                e0 = ee[0]; e1 = ee[1]; e2 = ee[2]; e3 = ee[3];
            }
            rs += (e0 + e1) + (e2 + e3);
            pw[nt][0] = pkbf(e0, e1);
            pw[nt][1] = pkbf(e2, e3);
        }

        // In-register P^T redistribution (R4-verified lane algebra).
        short8 pa;
        {
            union { u32 w[4]; short8 s; } P;
            #pragma unroll
            for (int w = 0; w < 2; ++w) {
                auto r = __builtin_amdgcn_permlane32_swap(
                    pw[0][w], pw[1][w], false, false);
                const u32 rx = r[0], ry = r[1];
                const u32 sx = (u32)__shfl_xor((int)rx, 16);
                const u32 sy = (u32)__shfl_xor((int)ry, 16);
                P.w[w]     = oddq ? sy : rx;
                P.w[2 + w] = oddq ? ry : sx;
            }
            pa = P.s;
        }

        __builtin_amdgcn_s_setprio(1);
        #pragma unroll
        for (int nt = 0; nt < 8; ++nt) {
            short8 vf = *(const short8*)&Vb[slot][nt][lane * 8];
            O[nt] = MFMA16(vf, pa, O[nt], 0, 0, 0);
        }
        __builtin_amdgcn_s_setprio(0);
    }
    #undef STAGE

    __asm__ volatile("s_waitcnt vmcnt(0)" ::: "memory");

    rs += __shfl_xor(rs, 16);
    rs += __shfl_xor(rs, 32);

    {
        const float inv = 1.0f / rs;
        u16* dst = ah + (rowb + q0 + mrow * 16 + lr) * (size_t)ATT_LD
                   + h * DIM_;
        #pragma unroll
        for (int nt = 0; nt < 8; ++nt) {
            uint2 o;
            o.x = pkbf(O[nt][0] * inv, O[nt][1] * inv);
            o.y = pkbf(O[nt][2] * inv, O[nt][3] * inv);
            *(uint2*)(dst + nt * 16 + quad * 4) = o;
        }
    }
}

// ---------- GEMM2 v3: LDS-ring tiled GEMM (attn skeleton) ------------------
// M=8192 N=128 K=2048. Block = 64 rows x 128 cols, FULL K (no split-K, no
// reduction). 8 waves (2x4): wave = 32r x 32c, acc 2x2 f32x4 = 16 AGPR.
// BK=64: A-tile 8KB (8 subs) + W-tile 16KB (16 subs) per slot, 3-slot ring
// (72KB), depth-2 prefetch via gload_lds16 (3 loads/wave/step), vmcnt(3) +
// one barrier per step — the R5-proven pipeline. Kills R6/R7's serial
// load-latency chain (T ~= 150 + max(0,L-2T) ~ 220cyc/step vs ~1500).
// W re-read: 128 blocks x 512KB = 64MB L2 (was 256MB).
__global__ __launch_bounds__(512) void gemm2_mfma(
    const u16* __restrict__ ah, const u16* __restrict__ wpth,
    float* __restrict__ out)
{
    const int bm = blockIdx.x * 64;            // 128 blocks
    const int tid = threadIdx.x;
    const int wv8 = tid >> 6, lane = tid & 63;
    const int wr = wv8 >> 2, wc = wv8 & 3;     // 2 x 4 wave grid
    const int lr = lane & 15, quad = lane >> 4;
    const int lo = lr, hi = quad;

    __shared__ u16 At[3][8][512];    // 24KB  A 64r x 64k / slot, p = mt*2+s
    __shared__ u16 Wt[3][16][512];   // 48KB  W 128n x 64k / slot, p = nt*2+s

    #define G2STAGE(CH, SLOT) do {                                            \
        const int _jk = (CH) << 6;                                            \
        {   const int _mt = wv8 >> 1, _s = wv8 & 1;   /* A sub p = wv8 */     \
            gload_lds16(ah + (size_t)(bm + _mt * 16 + lo) * ATT_LD            \
                        + _jk + _s * 32 + hi * 8, &At[(SLOT)][wv8][0]); }     \
        _Pragma("unroll")                                                     \
        for (int _t = 0; _t < 2; ++_t) {              /* W subs wv8, wv8+8 */ \
            const int _p = wv8 + _t * 8;                                      \
            const int _nt = _p >> 1, _s = _p & 1;                             \
            gload_lds16(wpth + (size_t)(_nt * 16 + lo) * ATT_LD               \
                        + _jk + _s * 32 + hi * 8, &Wt[(SLOT)][_p][0]);        \
        }                                                                     \
    } while (0)

    f32x4 acc[2][2] = {};

    G2STAGE(0, 0);
    G2STAGE(1, 1);

    for (int ch = 0; ch < 32; ++ch) {
        const int slot = ch % 3;
        __asm__ volatile("s_waitcnt vmcnt(3)" ::: "memory");
        __asm__ volatile("s_barrier" ::: "memory");   // step ch staged everywhere
        { const int cn = (ch + 2 < 32) ? (ch + 2) : 31;
          G2STAGE(cn, (ch + 2) % 3); }

        #pragma unroll
        for (int s = 0; s < 2; ++s) {
            short8 af[2], wf[2];
            #pragma unroll
            for (int mt = 0; mt < 2; ++mt)
                af[mt] = *(const short8*)&At[slot][(wr * 2 + mt) * 2 + s][lane * 8];
            #pragma unroll
            for (int nt = 0; nt < 2; ++nt)
                wf[nt] = *(const short8*)&Wt[slot][(wc * 2 + nt) * 2 + s][lane * 8];
            __builtin_amdgcn_s_setprio(1);
            #pragma unroll
            for (int mt = 0; mt < 2; ++mt)
                #pragma unroll
                for (int nt = 0; nt < 2; ++nt)
                    acc[mt][nt] = MFMA16(wf[nt], af[mt], acc[mt][nt], 0, 0, 0);
            __builtin_amdgcn_s_setprio(0);
        }
    }
    #undef G2STAGE

    __asm__ volatile("s_waitcnt vmcnt(0)" ::: "memory");

    #pragma unroll
    for (int mt = 0; mt < 2; ++mt)
        #pragma unroll
        for (int nt = 0; nt < 2; ++nt) {
            float* orow = out + (size_t)(bm + (wr * 2 + mt) * 16 + lr) * DIM_
                          + (wc * 2 + nt) * 16 + quad * 4;
            *(float4*)orow = *(float4*)&acc[mt][nt];
        }
}

// ---------- launch ----------------------------------------------------------
extern "C" void kernel_launch(void* const* d_in, const int* in_sizes, int n_in,
                              void* d_out, int out_size, void* d_ws, size_t ws_size,
                              hipStream_t stream)
{
    const float* x     = (const float*)d_in[0];
    const float* Wqkv  = (const float*)d_in[1];
    const float* Wproj = (const float*)d_in[2];
    float* out = (float*)d_out;

    u16* xh   = (u16*)d_ws;
    u16* wth  = xh   + (size_t)NX;
    u16* wpth = wth  + (size_t)NWQ;
    u16* qkvb = wpth + (size_t)NWP;                         // 8192*3072
    u16* vg   = qkvb + (size_t)8192 * QKV_LD;               // 4*4*128*2048
    u16* ahp  = vg   + (size_t)BATCH_ * KVH_ * DIM_ * SEQ_; // 8192*2048

    prep<<<1024 + 640, 256, 0, stream>>>(x, Wqkv, Wproj, xh, wth, wpth);

    gemm1_mfma<<<dim3(48, 16), 256, 0, stream>>>(xh, wth, qkvb, vg);

    attn_mfma<<<512, 512, 0, stream>>>(qkvb, vg, ahp, 0);
    attn_mfma<<<512, 512, 0, stream>>>(qkvb, vg, ahp, 32);

    gemm2_mfma<<<8192 / 64, 512, 0, stream>>>(ahp, wpth, out);
}